// Round 2
// baseline (604.662 us; speedup 1.0000x reference)
//
#include <hip/hip_runtime.h>

#define F_IN 128
#define HID 64
#define HEADS 4
#define NC 8

// ---------------------------------------------------------------- init / CSR

__global__ void k_init(int* __restrict__ deg, int N, int* __restrict__ counts, int NG) {
    int i = blockIdx.x * blockDim.x + threadIdx.x;
    if (i < N) deg[i] = 1;              // self loop contributes 1
    if (i < NG) counts[i] = 0;
}

__global__ void k_count(const int* __restrict__ ei, int E, int* __restrict__ deg) {
    int e = blockIdx.x * blockDim.x + threadIdx.x;
    if (e < E) atomicAdd(&deg[ei[E + e]], 1);   // dst row
}

__global__ void k_batch_count(const int* __restrict__ batch, int N, int* __restrict__ counts) {
    int i = blockIdx.x * blockDim.x + threadIdx.x;
    if (i < N) atomicAdd(&counts[batch[i]], 1);
}

// single-block exclusive scan, n arbitrary, block=1024; writes excl[0..n]
__global__ void k_scan(const int* __restrict__ v, int* __restrict__ excl, int n) {
    __shared__ int buf[1024];
    __shared__ int carry;
    int tid = threadIdx.x;
    if (tid == 0) carry = 0;
    __syncthreads();
    for (int base = 0; base < n; base += 1024) {
        int i = base + tid;
        int val = (i < n) ? v[i] : 0;
        buf[tid] = val;
        __syncthreads();
        for (int off = 1; off < 1024; off <<= 1) {
            int t = (tid >= off) ? buf[tid - off] : 0;
            __syncthreads();
            buf[tid] += t;
            __syncthreads();
        }
        if (i < n) excl[i] = carry + buf[tid] - val;
        __syncthreads();
        if (tid == 0) carry += buf[1023];
        __syncthreads();
    }
    if (tid == 0) excl[n] = carry;
}

__global__ void k_self(const int* __restrict__ rowstart, int* __restrict__ cursor,
                       int* __restrict__ csr, int N) {
    int i = blockIdx.x * blockDim.x + threadIdx.x;
    if (i < N) { csr[rowstart[i]] = i; cursor[i] = 1; }
}

__global__ void k_scatter(const int* __restrict__ ei, int E, const int* __restrict__ rowstart,
                          int* __restrict__ cursor, int* __restrict__ csr) {
    int e = blockIdx.x * blockDim.x + threadIdx.x;
    if (e < E) {
        int d = ei[E + e], s = ei[e];
        int pos = atomicAdd(&cursor[d], 1);
        csr[rowstart[d] + pos] = s;
    }
}

// ---------------------------------------------------------------- GEMMs (fp32, vector FMA)

// h1[n][256] = x[n][128] @ W1[128][256]; 16 nodes per block, 256 threads (col = tid)
__global__ __launch_bounds__(256) void k_gemm1(const float* __restrict__ x,
                                               const float* __restrict__ W1,
                                               float* __restrict__ h1, int N) {
    __shared__ float xs[F_IN][16];     // [k][m]
    int n0 = blockIdx.x * 16;
    int tid = threadIdx.x;
    int m  = tid >> 4;
    int k0 = (tid & 15) * 8;
    int row = n0 + m;
    if (row < N) {
        const float4* xp = (const float4*)(x + (size_t)row * F_IN + k0);
        float4 a = xp[0], b = xp[1];
        xs[k0 + 0][m] = a.x; xs[k0 + 1][m] = a.y; xs[k0 + 2][m] = a.z; xs[k0 + 3][m] = a.w;
        xs[k0 + 4][m] = b.x; xs[k0 + 5][m] = b.y; xs[k0 + 6][m] = b.z; xs[k0 + 7][m] = b.w;
    } else {
        #pragma unroll
        for (int j = 0; j < 8; j++) xs[k0 + j][m] = 0.f;
    }
    __syncthreads();
    float acc[16];
    #pragma unroll
    for (int q = 0; q < 16; q++) acc[q] = 0.f;
    const float* wp = W1 + tid;
    for (int k = 0; k < F_IN; k++) {
        float w = wp[k * 256];
        #pragma unroll
        for (int q = 0; q < 4; q++) {
            float4 xv = ((const float4*)&xs[k][0])[q];
            acc[4 * q + 0] += xv.x * w;
            acc[4 * q + 1] += xv.y * w;
            acc[4 * q + 2] += xv.z * w;
            acc[4 * q + 3] += xv.w * w;
        }
    }
    #pragma unroll
    for (int q = 0; q < 16; q++)
        if (n0 + q < N) h1[(size_t)(n0 + q) * 256 + tid] = acc[q];
}

// h2[n][64] = xin[n][256] @ W2[256][64]; 16 nodes per block, 64 threads (col = tid)
__global__ __launch_bounds__(64) void k_gemm2(const float* __restrict__ xin,
                                              const float* __restrict__ W2,
                                              float* __restrict__ h2, int N) {
    __shared__ float xs[256][16];      // [k][m]
    int n0 = blockIdx.x * 16;
    int tid = threadIdx.x;
    int m  = tid >> 2;
    int c0 = (tid & 3) * 64;
    int row = n0 + m;
    if (row < N) {
        const float* xr = xin + (size_t)row * 256 + c0;
        #pragma unroll
        for (int j = 0; j < 64; j += 4) {
            float4 v = *(const float4*)(xr + j);
            xs[c0 + j + 0][m] = v.x; xs[c0 + j + 1][m] = v.y;
            xs[c0 + j + 2][m] = v.z; xs[c0 + j + 3][m] = v.w;
        }
    } else {
        for (int j = 0; j < 64; j++) xs[c0 + j][m] = 0.f;
    }
    __syncthreads();
    float acc[16];
    #pragma unroll
    for (int q = 0; q < 16; q++) acc[q] = 0.f;
    const float* wp = W2 + tid;
    for (int k = 0; k < 256; k++) {
        float w = wp[k * 64];
        #pragma unroll
        for (int q = 0; q < 4; q++) {
            float4 xv = ((const float4*)&xs[k][0])[q];
            acc[4 * q + 0] += xv.x * w;
            acc[4 * q + 1] += xv.y * w;
            acc[4 * q + 2] += xv.z * w;
            acc[4 * q + 3] += xv.w * w;
        }
    }
    #pragma unroll
    for (int q = 0; q < 16; q++)
        if (n0 + q < N) h2[(size_t)(n0 + q) * 64 + tid] = acc[q];
}

// ---------------------------------------------------------------- attention coefs

// per node: a_s[n][h] = sum_c h1[n][h][c]*att_s[h][c]; block = 1 node, wave = head
__global__ __launch_bounds__(256) void k_att1(const float* __restrict__ h1,
                                              const float* __restrict__ atts,
                                              const float* __restrict__ attd,
                                              float* __restrict__ as, float* __restrict__ ad, int N) {
    int n = blockIdx.x;
    int tid = threadIdx.x;
    int head = tid >> 6, lane = tid & 63;
    float v = h1[(size_t)n * 256 + tid];
    float s = v * atts[tid];
    float d = v * attd[tid];
    #pragma unroll
    for (int off = 32; off > 0; off >>= 1) { s += __shfl_down(s, off); d += __shfl_down(d, off); }
    if (lane == 0) { as[n * 4 + head] = s; ad[n * 4 + head] = d; }
}

__global__ __launch_bounds__(256) void k_att2(const float* __restrict__ h2,
                                              const float* __restrict__ atts,
                                              const float* __restrict__ attd,
                                              float* __restrict__ as, float* __restrict__ ad, int N) {
    int n = blockIdx.x * 4 + (threadIdx.x >> 6);
    int lane = threadIdx.x & 63;
    if (n >= N) return;
    float v = h2[(size_t)n * 64 + lane];
    float s = v * atts[lane], d = v * attd[lane];
    #pragma unroll
    for (int off = 32; off > 0; off >>= 1) { s += __shfl_down(s, off); d += __shfl_down(d, off); }
    if (lane == 0) { as[n] = s; ad[n] = d; }
}

// ---------------------------------------------------------------- aggregation (1 wave / node)

__global__ __launch_bounds__(256) void k_agg1(const float* __restrict__ h1,
                                              const float* __restrict__ as, const float* __restrict__ ad,
                                              const int* __restrict__ rowstart, const int* __restrict__ csr,
                                              const float* __restrict__ b1,
                                              float* __restrict__ out1, int N) {
    int n = blockIdx.x * 4 + (threadIdx.x >> 6);
    int lane = threadIdx.x & 63;
    if (n >= N) return;
    int head = lane >> 4;
    int c0 = lane * 4;
    float adv = ad[n * 4 + head];
    int beg = rowstart[n], end = rowstart[n + 1];
    float4 acc = {0.f, 0.f, 0.f, 0.f};
    float ssum = 0.f;
    for (int j = beg; j < end; j++) {
        int s = csr[j];
        float e = as[s * 4 + head] + adv;
        e = (e > 0.f) ? e : 0.2f * e;           // leaky_relu 0.2
        float w = __expf(e);
        ssum += w;
        float4 hv = *(const float4*)(h1 + (size_t)s * 256 + c0);
        acc.x += w * hv.x; acc.y += w * hv.y; acc.z += w * hv.z; acc.w += w * hv.w;
    }
    float inv = 1.f / ssum;
    float o0 = acc.x * inv + b1[c0 + 0];
    float o1 = acc.y * inv + b1[c0 + 1];
    float o2 = acc.z * inv + b1[c0 + 2];
    float o3 = acc.w * inv + b1[c0 + 3];
    float4 o;                                    // fused +bias, relu
    o.x = o0 > 0.f ? o0 : 0.f; o.y = o1 > 0.f ? o1 : 0.f;
    o.z = o2 > 0.f ? o2 : 0.f; o.w = o3 > 0.f ? o3 : 0.f;
    *(float4*)(out1 + (size_t)n * 256 + c0) = o;
}

__global__ __launch_bounds__(256) void k_agg2(const float* __restrict__ h2,
                                              const float* __restrict__ as, const float* __restrict__ ad,
                                              const int* __restrict__ rowstart, const int* __restrict__ csr,
                                              const float* __restrict__ b2,
                                              float* __restrict__ out2, int N) {
    int n = blockIdx.x * 4 + (threadIdx.x >> 6);
    int lane = threadIdx.x & 63;
    if (n >= N) return;
    float adv = ad[n];
    int beg = rowstart[n], end = rowstart[n + 1];
    float acc = 0.f, ssum = 0.f;
    for (int j = beg; j < end; j++) {
        int s = csr[j];
        float e = as[s] + adv;
        e = (e > 0.f) ? e : 0.2f * e;
        float w = __expf(e);
        ssum += w;
        acc += w * h2[(size_t)s * 64 + lane];
    }
    float o = acc / ssum + b2[lane];
    out2[(size_t)n * 64 + lane] = o > 0.f ? o : 0.f;
}

// ---------------------------------------------------------------- pool + final linear

__global__ __launch_bounds__(64) void k_pool(const float* __restrict__ out2,
                                             const int* __restrict__ gstart,
                                             const float* __restrict__ lin_w,
                                             const float* __restrict__ lin_b,
                                             float* __restrict__ out, int NG) {
    __shared__ float mean[64];
    int g = blockIdx.x;
    int lane = threadIdx.x;
    int beg = gstart[g], end = gstart[g + 1];
    float s = 0.f;
    for (int n = beg; n < end; n++) s += out2[(size_t)n * 64 + lane];
    float cnt = (float)(end - beg);
    mean[lane] = s / fmaxf(cnt, 1.f);
    __syncthreads();
    if (lane < NC) {
        float acc = lin_b[lane];
        #pragma unroll
        for (int c = 0; c < 64; c++) acc += mean[c] * lin_w[c * NC + lane];
        out[g * NC + lane] = acc;
    }
}

// ---------------------------------------------------------------- launch

extern "C" void kernel_launch(void* const* d_in, const int* in_sizes, int n_in,
                              void* d_out, int out_size, void* d_ws, size_t ws_size,
                              hipStream_t stream) {
    const float* x      = (const float*)d_in[0];
    const int*   ei     = (const int*)d_in[1];
    const int*   batch  = (const int*)d_in[2];
    const float* W1     = (const float*)d_in[3];
    const float* att_s1 = (const float*)d_in[4];
    const float* att_d1 = (const float*)d_in[5];
    const float* b1     = (const float*)d_in[6];
    const float* W2     = (const float*)d_in[7];
    const float* att_s2 = (const float*)d_in[8];
    const float* att_d2 = (const float*)d_in[9];
    const float* b2     = (const float*)d_in[10];
    const float* lin_w  = (const float*)d_in[11];
    const float* lin_b  = (const float*)d_in[12];
    float* out = (float*)d_out;

    const int N  = in_sizes[0] / F_IN;   // 50000
    const int E  = in_sizes[1] / 2;      // 800000
    const int NG = out_size / NC;        // 512
    const int NE = E + N;

    char* p = (char*)d_ws;
    auto alloc = [&](size_t bytes) { char* r = p; p += (bytes + 255) & ~(size_t)255; return r; };
    float* h1       = (float*)alloc(sizeof(float) * (size_t)N * 256);
    float* out1     = (float*)alloc(sizeof(float) * (size_t)N * 256);
    float* as1      = (float*)alloc(sizeof(float) * (size_t)N * 4);
    float* ad1      = (float*)alloc(sizeof(float) * (size_t)N * 4);
    int*   rowstart = (int*)alloc(sizeof(int) * (size_t)(N + 1));
    int*   itmp     = (int*)alloc(sizeof(int) * (size_t)N);      // deg, then cursor
    int*   csr      = (int*)alloc(sizeof(int) * (size_t)NE);
    int*   counts   = (int*)alloc(sizeof(int) * (size_t)NG);
    int*   gstart   = (int*)alloc(sizeof(int) * (size_t)(NG + 1));
    // layer-2 tensors alias h1 (dead after layer-1 aggregation):
    float* h2   = h1;                     // N*64
    float* out2 = h1 + (size_t)N * 64;    // N*64
    float* as2  = h1 + (size_t)N * 128;   // N
    float* ad2  = h1 + (size_t)N * 128 + N;

    int bs = 256;
    // CSR build + batch counts
    k_init<<<(N + bs - 1) / bs, bs, 0, stream>>>(itmp, N, counts, NG);
    k_count<<<(E + bs - 1) / bs, bs, 0, stream>>>(ei, E, itmp);
    k_batch_count<<<(N + bs - 1) / bs, bs, 0, stream>>>(batch, N, counts);
    k_scan<<<1, 1024, 0, stream>>>(itmp, rowstart, N);
    k_scan<<<1, 1024, 0, stream>>>(counts, gstart, NG);
    k_self<<<(N + bs - 1) / bs, bs, 0, stream>>>(rowstart, itmp, csr, N);
    k_scatter<<<(E + bs - 1) / bs, bs, 0, stream>>>(ei, E, rowstart, itmp, csr);

    // layer 1
    k_gemm1<<<(N + 15) / 16, 256, 0, stream>>>(x, W1, h1, N);
    k_att1<<<N, 256, 0, stream>>>(h1, att_s1, att_d1, as1, ad1, N);
    k_agg1<<<(N + 3) / 4, 256, 0, stream>>>(h1, as1, ad1, rowstart, csr, b1, out1, N);

    // layer 2 (h2/out2/as2/ad2 alias h1 region)
    k_gemm2<<<(N + 15) / 16, 64, 0, stream>>>(out1, W2, h2, N);
    k_att2<<<(N + 3) / 4, 256, 0, stream>>>(h2, att_s2, att_d2, as2, ad2, N);
    k_agg2<<<(N + 3) / 4, 256, 0, stream>>>(h2, as2, ad2, rowstart, csr, b2, out2, N);

    // pool + linear
    k_pool<<<NG, 64, 0, stream>>>(out2, gstart, lin_w, lin_b, out, NG);
}

// Round 3
// 464.564 us; speedup vs baseline: 1.3016x; 1.3016x over previous
//
#include <hip/hip_runtime.h>

#define F_IN 128
#define HID 64
#define HEADS 4
#define NC 8

// ---------------------------------------------------------------- helpers

__device__ __forceinline__ ushort f2bf(float f) {      // RNE round to bf16
    uint u = __float_as_uint(f);
    return (ushort)((u + 0x7fffu + ((u >> 16) & 1u)) >> 16);
}
__device__ __forceinline__ float bf2f(ushort h) {
    return __uint_as_float(((uint)h) << 16);
}
__device__ __forceinline__ float edgew(float e) {      // exp(leaky_relu(e, 0.2))
    e = (e > 0.f) ? e : 0.2f * e;
    return __expf(e);
}

// ---------------------------------------------------------------- init / CSR

__global__ void k_init(int* __restrict__ deg, int N, int* __restrict__ counts, int NG) {
    int i = blockIdx.x * blockDim.x + threadIdx.x;
    if (i < N) deg[i] = 1;              // self loop contributes 1
    if (i < NG) counts[i] = 0;
}

__global__ void k_count(const int* __restrict__ ei, int E, int* __restrict__ deg) {
    int e = blockIdx.x * blockDim.x + threadIdx.x;
    if (e < E) atomicAdd(&deg[ei[E + e]], 1);   // dst row
}

__global__ void k_batch_count(const int* __restrict__ batch, int N, int* __restrict__ counts) {
    int i = blockIdx.x * blockDim.x + threadIdx.x;
    if (i < N) atomicAdd(&counts[batch[i]], 1);
}

// hierarchical scan: part (per 1024-block excl + block total), bsum scan, add
__global__ __launch_bounds__(1024) void k_scan_part(const int* __restrict__ v,
                                                    int* __restrict__ excl,
                                                    int* __restrict__ bsum, int n) {
    __shared__ int buf[1024];
    int tid = threadIdx.x;
    int i = blockIdx.x * 1024 + tid;
    int val = (i < n) ? v[i] : 0;
    buf[tid] = val;
    __syncthreads();
    for (int off = 1; off < 1024; off <<= 1) {
        int t = (tid >= off) ? buf[tid - off] : 0;
        __syncthreads();
        buf[tid] += t;
        __syncthreads();
    }
    if (i < n) excl[i] = buf[tid] - val;
    if (tid == 1023) bsum[blockIdx.x] = buf[1023];
}

__global__ __launch_bounds__(1024) void k_scan_bsum(const int* __restrict__ bsum,
                                                    int* __restrict__ boff, int nb,
                                                    int* __restrict__ total_out) {
    __shared__ int buf[1024];
    int tid = threadIdx.x;
    int val = (tid < nb) ? bsum[tid] : 0;
    buf[tid] = val;
    __syncthreads();
    for (int off = 1; off < 1024; off <<= 1) {
        int t = (tid >= off) ? buf[tid - off] : 0;
        __syncthreads();
        buf[tid] += t;
        __syncthreads();
    }
    if (tid < nb) boff[tid] = buf[tid] - val;
    if (tid == 1023) total_out[0] = buf[1023];
}

__global__ void k_scan_add(int* __restrict__ excl, const int* __restrict__ boff, int n) {
    int i = blockIdx.x * blockDim.x + threadIdx.x;
    if (i < n) excl[i] += boff[i >> 10];
}

// single-block scan for small arrays (NG=512); writes excl[0..n]
__global__ __launch_bounds__(1024) void k_scan(const int* __restrict__ v, int* __restrict__ excl, int n) {
    __shared__ int buf[1024];
    int tid = threadIdx.x;
    int val = (tid < n) ? v[tid] : 0;
    buf[tid] = val;
    __syncthreads();
    for (int off = 1; off < 1024; off <<= 1) {
        int t = (tid >= off) ? buf[tid - off] : 0;
        __syncthreads();
        buf[tid] += t;
        __syncthreads();
    }
    if (tid < n) excl[tid] = buf[tid] - val;
    if (tid == 1023) excl[n] = buf[1023];
}

__global__ void k_self(const int* __restrict__ rowstart, int* __restrict__ cursor,
                       int* __restrict__ csr, int N) {
    int i = blockIdx.x * blockDim.x + threadIdx.x;
    if (i < N) { csr[rowstart[i]] = i; cursor[i] = 1; }
}

__global__ void k_scatter(const int* __restrict__ ei, int E, const int* __restrict__ rowstart,
                          int* __restrict__ cursor, int* __restrict__ csr) {
    int e = blockIdx.x * blockDim.x + threadIdx.x;
    if (e < E) {
        int d = ei[E + e], s = ei[e];
        int pos = atomicAdd(&cursor[d], 1);
        csr[rowstart[d] + pos] = s;
    }
}

// ---------------------------------------------------------------- layer-1 GEMM + fused att
// h1 = x[N][128] @ W1[128][256]; writes h1 as bf16, a_s/a_d per (node, head).
// 64-node tile, 256 threads, col = tid, wave = head.
__global__ __launch_bounds__(256) void k_gemm1(const float* __restrict__ x,
                                               const float* __restrict__ W1,
                                               const float* __restrict__ atts,
                                               const float* __restrict__ attd,
                                               ushort* __restrict__ h1b,
                                               float* __restrict__ as1, float* __restrict__ ad1,
                                               int N) {
    __shared__ float xs[F_IN][64];     // 32 KB, [k][m]
    int n0 = blockIdx.x * 64;
    int tid = threadIdx.x;
    // load x tile: 64 rows x 128 cols; thread -> row tid>>2, cols (tid&3)*32..+32
    {
        int m = tid >> 2;
        int k0 = (tid & 3) * 32;
        int row = n0 + m;
        if (row < N) {
            const float4* xp = (const float4*)(x + (size_t)row * F_IN + k0);
            #pragma unroll
            for (int j = 0; j < 8; j++) {
                float4 v = xp[j];
                int kk = k0 + j * 4;
                xs[kk + 0][m] = v.x; xs[kk + 1][m] = v.y;
                xs[kk + 2][m] = v.z; xs[kk + 3][m] = v.w;
            }
        } else {
            #pragma unroll
            for (int j = 0; j < 32; j++) xs[k0 + j][m] = 0.f;
        }
    }
    __syncthreads();
    float acc[64];
    #pragma unroll
    for (int q = 0; q < 64; q++) acc[q] = 0.f;
    const float* wp = W1 + tid;
    for (int k = 0; k < F_IN; k++) {
        float w = wp[k * 256];
        #pragma unroll
        for (int mm = 0; mm < 64; mm += 4) {
            float4 xv = *(const float4*)&xs[k][mm];
            acc[mm + 0] += xv.x * w;
            acc[mm + 1] += xv.y * w;
            acc[mm + 2] += xv.z * w;
            acc[mm + 3] += xv.w * w;
        }
    }
    // epilogue: bf16 store + fused attention-coef reduction (wave == head)
    int head = tid >> 6, lane = tid & 63;
    float av_s = atts[tid], av_d = attd[tid];
    #pragma unroll 4
    for (int mm = 0; mm < 64; mm++) {
        int n = n0 + mm;
        float a = acc[mm];
        float s = a * av_s, d = a * av_d;
        #pragma unroll
        for (int off = 32; off > 0; off >>= 1) {
            s += __shfl_down(s, off);
            d += __shfl_down(d, off);
        }
        if (n < N) {
            h1b[(size_t)n * 256 + tid] = f2bf(a);
            if (lane == 0) { as1[n * 4 + head] = s; ad1[n * 4 + head] = d; }
        }
    }
}

// ---------------------------------------------------------------- layer-2 GEMM + fused att
// h2 = out1[N][256] @ W2[256][64]; 32-node tile, 256 threads: col=tid&63, wave q owns 8 nodes.
__global__ __launch_bounds__(256) void k_gemm2(const float* __restrict__ xin,
                                               const float* __restrict__ W2,
                                               const float* __restrict__ atts,
                                               const float* __restrict__ attd,
                                               ushort* __restrict__ h2b,
                                               float* __restrict__ as2, float* __restrict__ ad2,
                                               int N) {
    __shared__ float xs[256][32];      // 32 KB, [k][m]
    int n0 = blockIdx.x * 32;
    int tid = threadIdx.x;
    {
        int m = tid >> 3;              // 0..31
        int k0 = (tid & 7) * 32;       // 0..224
        int row = n0 + m;
        if (row < N) {
            const float4* xp = (const float4*)(xin + (size_t)row * 256 + k0);
            #pragma unroll
            for (int j = 0; j < 8; j++) {
                float4 v = xp[j];
                int kk = k0 + j * 4;
                xs[kk + 0][m] = v.x; xs[kk + 1][m] = v.y;
                xs[kk + 2][m] = v.z; xs[kk + 3][m] = v.w;
            }
        } else {
            #pragma unroll
            for (int j = 0; j < 32; j++) xs[k0 + j][m] = 0.f;
        }
    }
    __syncthreads();
    int col = tid & 63, q = tid >> 6;
    int mbase = q * 8;
    float acc[8];
    #pragma unroll
    for (int j = 0; j < 8; j++) acc[j] = 0.f;
    const float* wp = W2 + col;
    for (int k = 0; k < 256; k++) {
        float w = wp[k * 64];
        float4 xa = *(const float4*)&xs[k][mbase];
        float4 xb = *(const float4*)&xs[k][mbase + 4];
        acc[0] += xa.x * w; acc[1] += xa.y * w; acc[2] += xa.z * w; acc[3] += xa.w * w;
        acc[4] += xb.x * w; acc[5] += xb.y * w; acc[6] += xb.z * w; acc[7] += xb.w * w;
    }
    float av_s = atts[col], av_d = attd[col];
    #pragma unroll
    for (int mm = 0; mm < 8; mm++) {
        int n = n0 + mbase + mm;
        float a = acc[mm];
        float s = a * av_s, d = a * av_d;
        #pragma unroll
        for (int off = 32; off > 0; off >>= 1) {
            s += __shfl_down(s, off);
            d += __shfl_down(d, off);
        }
        if (n < N) {
            h2b[(size_t)n * 64 + col] = f2bf(a);
            if (col == 0) { as2[n] = s; ad2[n] = d; }
        }
    }
}

// ---------------------------------------------------------------- aggregation (1 wave / node)

__global__ __launch_bounds__(256) void k_agg1(const ushort* __restrict__ h1b,
                                              const float* __restrict__ as, const float* __restrict__ ad,
                                              const int* __restrict__ rowstart, const int* __restrict__ csr,
                                              const float* __restrict__ b1,
                                              float* __restrict__ out1, int N) {
    int n = blockIdx.x * 4 + (threadIdx.x >> 6);
    int lane = threadIdx.x & 63;
    if (n >= N) return;
    int head = lane >> 4;
    int coff = lane * 4;
    float adv = ad[n * 4 + head];
    int beg = rowstart[n], end = rowstart[n + 1];
    float a0 = 0.f, a1 = 0.f, a2 = 0.f, a3 = 0.f, ssum = 0.f;
    int j = beg;
    for (; j + 4 <= end; j += 4) {
        int s0 = csr[j + 0], s1 = csr[j + 1], s2 = csr[j + 2], s3 = csr[j + 3];
        float e0 = as[s0 * 4 + head], e1 = as[s1 * 4 + head];
        float e2 = as[s2 * 4 + head], e3 = as[s3 * 4 + head];
        ushort4 v0 = *(const ushort4*)(h1b + (size_t)s0 * 256 + coff);
        ushort4 v1 = *(const ushort4*)(h1b + (size_t)s1 * 256 + coff);
        ushort4 v2 = *(const ushort4*)(h1b + (size_t)s2 * 256 + coff);
        ushort4 v3 = *(const ushort4*)(h1b + (size_t)s3 * 256 + coff);
        float w0 = edgew(e0 + adv), w1 = edgew(e1 + adv);
        float w2 = edgew(e2 + adv), w3 = edgew(e3 + adv);
        ssum += (w0 + w1) + (w2 + w3);
        a0 += w0 * bf2f(v0.x) + w1 * bf2f(v1.x) + w2 * bf2f(v2.x) + w3 * bf2f(v3.x);
        a1 += w0 * bf2f(v0.y) + w1 * bf2f(v1.y) + w2 * bf2f(v2.y) + w3 * bf2f(v3.y);
        a2 += w0 * bf2f(v0.z) + w1 * bf2f(v1.z) + w2 * bf2f(v2.z) + w3 * bf2f(v3.z);
        a3 += w0 * bf2f(v0.w) + w1 * bf2f(v1.w) + w2 * bf2f(v2.w) + w3 * bf2f(v3.w);
    }
    for (; j < end; j++) {
        int s0 = csr[j];
        float w0 = edgew(as[s0 * 4 + head] + adv);
        ushort4 v0 = *(const ushort4*)(h1b + (size_t)s0 * 256 + coff);
        ssum += w0;
        a0 += w0 * bf2f(v0.x); a1 += w0 * bf2f(v0.y);
        a2 += w0 * bf2f(v0.z); a3 += w0 * bf2f(v0.w);
    }
    float inv = 1.f / ssum;
    float o0 = a0 * inv + b1[coff + 0];
    float o1 = a1 * inv + b1[coff + 1];
    float o2 = a2 * inv + b1[coff + 2];
    float o3 = a3 * inv + b1[coff + 3];
    float4 o;
    o.x = o0 > 0.f ? o0 : 0.f; o.y = o1 > 0.f ? o1 : 0.f;
    o.z = o2 > 0.f ? o2 : 0.f; o.w = o3 > 0.f ? o3 : 0.f;
    *(float4*)(out1 + (size_t)n * 256 + coff) = o;
}

__global__ __launch_bounds__(256) void k_agg2(const ushort* __restrict__ h2b,
                                              const float* __restrict__ as, const float* __restrict__ ad,
                                              const int* __restrict__ rowstart, const int* __restrict__ csr,
                                              const float* __restrict__ b2,
                                              float* __restrict__ out2, int N) {
    int n = blockIdx.x * 4 + (threadIdx.x >> 6);
    int lane = threadIdx.x & 63;
    if (n >= N) return;
    float adv = ad[n];
    int beg = rowstart[n], end = rowstart[n + 1];
    float acc = 0.f, ssum = 0.f;
    int j = beg;
    for (; j + 4 <= end; j += 4) {
        int s0 = csr[j + 0], s1 = csr[j + 1], s2 = csr[j + 2], s3 = csr[j + 3];
        float e0 = as[s0], e1 = as[s1], e2 = as[s2], e3 = as[s3];
        ushort v0 = h2b[(size_t)s0 * 64 + lane];
        ushort v1 = h2b[(size_t)s1 * 64 + lane];
        ushort v2 = h2b[(size_t)s2 * 64 + lane];
        ushort v3 = h2b[(size_t)s3 * 64 + lane];
        float w0 = edgew(e0 + adv), w1 = edgew(e1 + adv);
        float w2 = edgew(e2 + adv), w3 = edgew(e3 + adv);
        ssum += (w0 + w1) + (w2 + w3);
        acc += w0 * bf2f(v0) + w1 * bf2f(v1) + w2 * bf2f(v2) + w3 * bf2f(v3);
    }
    for (; j < end; j++) {
        int s0 = csr[j];
        float w0 = edgew(as[s0] + adv);
        ssum += w0;
        acc += w0 * bf2f(h2b[(size_t)s0 * 64 + lane]);
    }
    float o = acc / ssum + b2[lane];
    out2[(size_t)n * 64 + lane] = o > 0.f ? o : 0.f;
}

// ---------------------------------------------------------------- pool + final linear

__global__ __launch_bounds__(64) void k_pool(const float* __restrict__ out2,
                                             const int* __restrict__ gstart,
                                             const float* __restrict__ lin_w,
                                             const float* __restrict__ lin_b,
                                             float* __restrict__ out, int NG) {
    __shared__ float mean[64];
    int g = blockIdx.x;
    int lane = threadIdx.x;
    int beg = gstart[g], end = gstart[g + 1];
    float s = 0.f;
    for (int n = beg; n < end; n++) s += out2[(size_t)n * 64 + lane];
    float cnt = (float)(end - beg);
    mean[lane] = s / fmaxf(cnt, 1.f);
    __syncthreads();
    if (lane < NC) {
        float acc = lin_b[lane];
        #pragma unroll
        for (int c = 0; c < 64; c++) acc += mean[c] * lin_w[c * NC + lane];
        out[g * NC + lane] = acc;
    }
}

// ---------------------------------------------------------------- launch

extern "C" void kernel_launch(void* const* d_in, const int* in_sizes, int n_in,
                              void* d_out, int out_size, void* d_ws, size_t ws_size,
                              hipStream_t stream) {
    const float* x      = (const float*)d_in[0];
    const int*   ei     = (const int*)d_in[1];
    const int*   batch  = (const int*)d_in[2];
    const float* W1     = (const float*)d_in[3];
    const float* att_s1 = (const float*)d_in[4];
    const float* att_d1 = (const float*)d_in[5];
    const float* b1     = (const float*)d_in[6];
    const float* W2     = (const float*)d_in[7];
    const float* att_s2 = (const float*)d_in[8];
    const float* att_d2 = (const float*)d_in[9];
    const float* b2     = (const float*)d_in[10];
    const float* lin_w  = (const float*)d_in[11];
    const float* lin_b  = (const float*)d_in[12];
    float* out = (float*)d_out;

    const int N  = in_sizes[0] / F_IN;   // 50000
    const int E  = in_sizes[1] / 2;      // 800000
    const int NG = out_size / NC;        // 512
    const int NE = E + N;
    const int NB = (N + 1023) / 1024;    // scan blocks

    char* p = (char*)d_ws;
    auto alloc = [&](size_t bytes) { char* r = p; p += (bytes + 255) & ~(size_t)255; return r; };
    ushort* h1b     = (ushort*)alloc(sizeof(ushort) * (size_t)N * 256);
    float*  out1    = (float*)alloc(sizeof(float) * (size_t)N * 256);
    ushort* h2b     = (ushort*)alloc(sizeof(ushort) * (size_t)N * 64);
    float*  out2    = (float*)alloc(sizeof(float) * (size_t)N * 64);
    float*  as1     = (float*)alloc(sizeof(float) * (size_t)N * 4);
    float*  ad1     = (float*)alloc(sizeof(float) * (size_t)N * 4);
    float*  as2     = (float*)alloc(sizeof(float) * (size_t)N);
    float*  ad2     = (float*)alloc(sizeof(float) * (size_t)N);
    int*    rowstart= (int*)alloc(sizeof(int) * (size_t)(N + 1));
    int*    itmp    = (int*)alloc(sizeof(int) * (size_t)N);      // deg, then cursor
    int*    csr     = (int*)alloc(sizeof(int) * (size_t)NE);
    int*    counts  = (int*)alloc(sizeof(int) * (size_t)NG);
    int*    gstart  = (int*)alloc(sizeof(int) * (size_t)(NG + 1));
    int*    bsum    = (int*)alloc(sizeof(int) * 1024);
    int*    boff    = (int*)alloc(sizeof(int) * 1024);

    int bs = 256;
    // CSR build + batch counts
    k_init<<<(N + bs - 1) / bs, bs, 0, stream>>>(itmp, N, counts, NG);
    k_count<<<(E + bs - 1) / bs, bs, 0, stream>>>(ei, E, itmp);
    k_batch_count<<<(N + bs - 1) / bs, bs, 0, stream>>>(batch, N, counts);
    k_scan_part<<<NB, 1024, 0, stream>>>(itmp, rowstart, bsum, N);
    k_scan_bsum<<<1, 1024, 0, stream>>>(bsum, boff, NB, rowstart + N);
    k_scan_add<<<(N + 1023) / 1024, 1024, 0, stream>>>(rowstart, boff, N);
    k_scan<<<1, 1024, 0, stream>>>(counts, gstart, NG);
    k_self<<<(N + bs - 1) / bs, bs, 0, stream>>>(rowstart, itmp, csr, N);
    k_scatter<<<(E + bs - 1) / bs, bs, 0, stream>>>(ei, E, rowstart, itmp, csr);

    // layer 1 (GEMM + fused att coefs), then aggregate
    k_gemm1<<<(N + 63) / 64, 256, 0, stream>>>(x, W1, att_s1, att_d1, h1b, as1, ad1, N);
    k_agg1<<<(N + 3) / 4, 256, 0, stream>>>(h1b, as1, ad1, rowstart, csr, b1, out1, N);

    // layer 2
    k_gemm2<<<(N + 31) / 32, 256, 0, stream>>>(out1, W2, att_s2, att_d2, h2b, as2, ad2, N);
    k_agg2<<<(N + 3) / 4, 256, 0, stream>>>(h2b, as2, ad2, rowstart, csr, b2, out2, N);

    // pool + linear
    k_pool<<<NG, 64, 0, stream>>>(out2, gstart, lin_w, lin_b, out, NG);
}

// Round 4
// 407.320 us; speedup vs baseline: 1.4845x; 1.1405x over previous
//
#include <hip/hip_runtime.h>

#define F_IN 128
#define HID 64
#define HEADS 4
#define NC 8

// ---------------------------------------------------------------- helpers

__device__ __forceinline__ ushort f2bf(float f) {      // RNE round to bf16
    uint u = __float_as_uint(f);
    return (ushort)((u + 0x7fffu + ((u >> 16) & 1u)) >> 16);
}
__device__ __forceinline__ float bf2f(ushort h) {
    return __uint_as_float(((uint)h) << 16);
}
__device__ __forceinline__ float edgew(float e) {      // exp(leaky_relu(e, 0.2))
    e = (e > 0.f) ? e : 0.2f * e;
    return __expf(e);
}

// ---------------------------------------------------------------- init / CSR

__global__ void k_init(int* __restrict__ deg, int N, int* __restrict__ counts, int NG) {
    int i = blockIdx.x * blockDim.x + threadIdx.x;
    if (i < N) deg[i] = 1;              // self loop contributes 1
    if (i < NG) counts[i] = 0;
}

__global__ void k_count(const int* __restrict__ ei, int E, int* __restrict__ deg) {
    int e = blockIdx.x * blockDim.x + threadIdx.x;
    if (e < E) atomicAdd(&deg[ei[E + e]], 1);   // dst row
}

__global__ void k_batch_count(const int* __restrict__ batch, int N, int* __restrict__ counts) {
    int i = blockIdx.x * blockDim.x + threadIdx.x;
    if (i < N) atomicAdd(&counts[batch[i]], 1);
}

// hierarchical scan: part (per 1024-block excl + block total), bsum scan, add
__global__ __launch_bounds__(1024) void k_scan_part(const int* __restrict__ v,
                                                    int* __restrict__ excl,
                                                    int* __restrict__ bsum, int n) {
    __shared__ int buf[1024];
    int tid = threadIdx.x;
    int i = blockIdx.x * 1024 + tid;
    int val = (i < n) ? v[i] : 0;
    buf[tid] = val;
    __syncthreads();
    for (int off = 1; off < 1024; off <<= 1) {
        int t = (tid >= off) ? buf[tid - off] : 0;
        __syncthreads();
        buf[tid] += t;
        __syncthreads();
    }
    if (i < n) excl[i] = buf[tid] - val;
    if (tid == 1023) bsum[blockIdx.x] = buf[1023];
}

__global__ __launch_bounds__(1024) void k_scan_bsum(const int* __restrict__ bsum,
                                                    int* __restrict__ boff, int nb,
                                                    int* __restrict__ total_out) {
    __shared__ int buf[1024];
    int tid = threadIdx.x;
    int val = (tid < nb) ? bsum[tid] : 0;
    buf[tid] = val;
    __syncthreads();
    for (int off = 1; off < 1024; off <<= 1) {
        int t = (tid >= off) ? buf[tid - off] : 0;
        __syncthreads();
        buf[tid] += t;
        __syncthreads();
    }
    if (tid < nb) boff[tid] = buf[tid] - val;
    if (tid == 1023) total_out[0] = buf[1023];
}

// finalize rowstart (+= block offset) AND seed csr with self-loop + cursor=1
__global__ void k_scan_add_self(int* __restrict__ rowstart, const int* __restrict__ boff,
                                int* __restrict__ cursor, int* __restrict__ csr, int n) {
    int i = blockIdx.x * blockDim.x + threadIdx.x;
    if (i < n) {
        int rs = rowstart[i] + boff[i >> 10];
        rowstart[i] = rs;
        csr[rs] = i;          // self loop first
        cursor[i] = 1;
    }
}

// single-block scan for small arrays (NG=512); writes excl[0..n]
__global__ __launch_bounds__(1024) void k_scan(const int* __restrict__ v, int* __restrict__ excl, int n) {
    __shared__ int buf[1024];
    int tid = threadIdx.x;
    int val = (tid < n) ? v[tid] : 0;
    buf[tid] = val;
    __syncthreads();
    for (int off = 1; off < 1024; off <<= 1) {
        int t = (tid >= off) ? buf[tid - off] : 0;
        __syncthreads();
        buf[tid] += t;
        __syncthreads();
    }
    if (tid < n) excl[tid] = buf[tid] - val;
    if (tid == 1023) excl[n] = buf[1023];
}

__global__ void k_scatter(const int* __restrict__ ei, int E, const int* __restrict__ rowstart,
                          int* __restrict__ cursor, int* __restrict__ csr) {
    int e = blockIdx.x * blockDim.x + threadIdx.x;
    if (e < E) {
        int d = ei[E + e], s = ei[e];
        int pos = atomicAdd(&cursor[d], 1);
        csr[rowstart[d] + pos] = s;
    }
}

// ---------------------------------------------------------------- layer-1 GEMM + fused att
// h1 = x[N][128] @ W1[128][256]; writes h1 as bf16, a_s/a_d per (node, head).
// 32-node tile, 256 threads, col = tid, wave = head. acc[32] stays in VGPRs.
__global__ __launch_bounds__(256) void k_gemm1(const float* __restrict__ x,
                                               const float* __restrict__ W1,
                                               const float* __restrict__ atts,
                                               const float* __restrict__ attd,
                                               ushort* __restrict__ h1b,
                                               float* __restrict__ as1, float* __restrict__ ad1,
                                               int N) {
    __shared__ float xs[F_IN][36];     // stride 36: 16B-aligned float4 rows, spread banks
    int n0 = blockIdx.x * 32;
    int tid = threadIdx.x;
    {   // load x tile: 32 rows x 128 cols; thread -> row tid>>3, cols (tid&7)*16
        int m = tid >> 3;
        int k0 = (tid & 7) * 16;
        int row = n0 + m;
        if (row < N) {
            const float4* xp = (const float4*)(x + (size_t)row * F_IN + k0);
            #pragma unroll
            for (int j = 0; j < 4; j++) {
                float4 v = xp[j];
                int kk = k0 + j * 4;
                xs[kk + 0][m] = v.x; xs[kk + 1][m] = v.y;
                xs[kk + 2][m] = v.z; xs[kk + 3][m] = v.w;
            }
        } else {
            #pragma unroll
            for (int j = 0; j < 16; j++) xs[k0 + j][m] = 0.f;
        }
    }
    __syncthreads();
    float acc[32];
    #pragma unroll
    for (int q = 0; q < 32; q++) acc[q] = 0.f;
    const float* wp = W1 + tid;
    for (int k = 0; k < F_IN; k++) {
        float w = wp[k * 256];
        #pragma unroll
        for (int mm = 0; mm < 32; mm += 4) {
            float4 xv = *(const float4*)&xs[k][mm];
            acc[mm + 0] += xv.x * w;
            acc[mm + 1] += xv.y * w;
            acc[mm + 2] += xv.z * w;
            acc[mm + 3] += xv.w * w;
        }
    }
    // epilogue: bf16 store + fused attention-coef reduction (wave == head)
    int head = tid >> 6, lane = tid & 63;
    float av_s = atts[tid], av_d = attd[tid];
    #pragma unroll 4
    for (int mm = 0; mm < 32; mm++) {
        int n = n0 + mm;
        float a = acc[mm];
        float s = a * av_s, d = a * av_d;
        #pragma unroll
        for (int off = 32; off > 0; off >>= 1) {
            s += __shfl_down(s, off);
            d += __shfl_down(d, off);
        }
        if (n < N) {
            h1b[(size_t)n * 256 + tid] = f2bf(a);
            if (lane == 0) { as1[n * 4 + head] = s; ad1[n * 4 + head] = d; }
        }
    }
}

// ---------------------------------------------------------------- layer-2 GEMM + fused att
// h2 = out1[N][256] @ W2[256][64]; 32-node tile, 256 threads: col=tid&63, wave q owns 8 nodes.
__global__ __launch_bounds__(256) void k_gemm2(const float* __restrict__ xin,
                                               const float* __restrict__ W2,
                                               const float* __restrict__ atts,
                                               const float* __restrict__ attd,
                                               ushort* __restrict__ h2b,
                                               float* __restrict__ as2, float* __restrict__ ad2,
                                               int N) {
    __shared__ float xs[256][36];      // stride 36: aligned + bank spread
    int n0 = blockIdx.x * 32;
    int tid = threadIdx.x;
    {
        int m = tid >> 3;              // 0..31
        int k0 = (tid & 7) * 32;       // 0..224
        int row = n0 + m;
        if (row < N) {
            const float4* xp = (const float4*)(xin + (size_t)row * 256 + k0);
            #pragma unroll
            for (int j = 0; j < 8; j++) {
                float4 v = xp[j];
                int kk = k0 + j * 4;
                xs[kk + 0][m] = v.x; xs[kk + 1][m] = v.y;
                xs[kk + 2][m] = v.z; xs[kk + 3][m] = v.w;
            }
        } else {
            #pragma unroll
            for (int j = 0; j < 32; j++) xs[k0 + j][m] = 0.f;
        }
    }
    __syncthreads();
    int col = tid & 63, q = tid >> 6;
    int mbase = q * 8;
    float acc[8];
    #pragma unroll
    for (int j = 0; j < 8; j++) acc[j] = 0.f;
    const float* wp = W2 + col;
    for (int k = 0; k < 256; k++) {
        float w = wp[k * 64];
        float4 xa = *(const float4*)&xs[k][mbase];
        float4 xb = *(const float4*)&xs[k][mbase + 4];
        acc[0] += xa.x * w; acc[1] += xa.y * w; acc[2] += xa.z * w; acc[3] += xa.w * w;
        acc[4] += xb.x * w; acc[5] += xb.y * w; acc[6] += xb.z * w; acc[7] += xb.w * w;
    }
    float av_s = atts[col], av_d = attd[col];
    #pragma unroll
    for (int mm = 0; mm < 8; mm++) {
        int n = n0 + mbase + mm;
        float a = acc[mm];
        float s = a * av_s, d = a * av_d;
        #pragma unroll
        for (int off = 32; off > 0; off >>= 1) {
            s += __shfl_down(s, off);
            d += __shfl_down(d, off);
        }
        if (n < N) {
            h2b[(size_t)n * 64 + col] = f2bf(a);
            if (col == 0) { as2[n] = s; ad2[n] = d; }
        }
    }
}

// ---------------------------------------------------------------- aggregation (1 wave / node)

__global__ __launch_bounds__(256) void k_agg1(const ushort* __restrict__ h1b,
                                              const float* __restrict__ as, const float* __restrict__ ad,
                                              const int* __restrict__ rowstart, const int* __restrict__ csr,
                                              const float* __restrict__ b1,
                                              float* __restrict__ out1, int N) {
    int n = blockIdx.x * 4 + (threadIdx.x >> 6);
    int lane = threadIdx.x & 63;
    if (n >= N) return;
    int head = lane >> 4;
    int coff = lane * 4;
    float adv = ad[n * 4 + head];
    int beg = rowstart[n], end = rowstart[n + 1];
    float a0 = 0.f, a1 = 0.f, a2 = 0.f, a3 = 0.f, ssum = 0.f;
    int j = beg;
    for (; j + 4 <= end; j += 4) {
        int s0 = csr[j + 0], s1 = csr[j + 1], s2 = csr[j + 2], s3 = csr[j + 3];
        float e0 = as[s0 * 4 + head], e1 = as[s1 * 4 + head];
        float e2 = as[s2 * 4 + head], e3 = as[s3 * 4 + head];
        ushort4 v0 = *(const ushort4*)(h1b + (size_t)s0 * 256 + coff);
        ushort4 v1 = *(const ushort4*)(h1b + (size_t)s1 * 256 + coff);
        ushort4 v2 = *(const ushort4*)(h1b + (size_t)s2 * 256 + coff);
        ushort4 v3 = *(const ushort4*)(h1b + (size_t)s3 * 256 + coff);
        float w0 = edgew(e0 + adv), w1 = edgew(e1 + adv);
        float w2 = edgew(e2 + adv), w3 = edgew(e3 + adv);
        ssum += (w0 + w1) + (w2 + w3);
        a0 += w0 * bf2f(v0.x) + w1 * bf2f(v1.x) + w2 * bf2f(v2.x) + w3 * bf2f(v3.x);
        a1 += w0 * bf2f(v0.y) + w1 * bf2f(v1.y) + w2 * bf2f(v2.y) + w3 * bf2f(v3.y);
        a2 += w0 * bf2f(v0.z) + w1 * bf2f(v1.z) + w2 * bf2f(v2.z) + w3 * bf2f(v3.z);
        a3 += w0 * bf2f(v0.w) + w1 * bf2f(v1.w) + w2 * bf2f(v2.w) + w3 * bf2f(v3.w);
    }
    for (; j < end; j++) {
        int s0 = csr[j];
        float w0 = edgew(as[s0 * 4 + head] + adv);
        ushort4 v0 = *(const ushort4*)(h1b + (size_t)s0 * 256 + coff);
        ssum += w0;
        a0 += w0 * bf2f(v0.x); a1 += w0 * bf2f(v0.y);
        a2 += w0 * bf2f(v0.z); a3 += w0 * bf2f(v0.w);
    }
    float inv = 1.f / ssum;
    float o0 = a0 * inv + b1[coff + 0];
    float o1 = a1 * inv + b1[coff + 1];
    float o2 = a2 * inv + b1[coff + 2];
    float o3 = a3 * inv + b1[coff + 3];
    float4 o;
    o.x = o0 > 0.f ? o0 : 0.f; o.y = o1 > 0.f ? o1 : 0.f;
    o.z = o2 > 0.f ? o2 : 0.f; o.w = o3 > 0.f ? o3 : 0.f;
    *(float4*)(out1 + (size_t)n * 256 + coff) = o;
}

__global__ __launch_bounds__(256) void k_agg2(const ushort* __restrict__ h2b,
                                              const float* __restrict__ as, const float* __restrict__ ad,
                                              const int* __restrict__ rowstart, const int* __restrict__ csr,
                                              const float* __restrict__ b2,
                                              float* __restrict__ out2, int N) {
    int n = blockIdx.x * 4 + (threadIdx.x >> 6);
    int lane = threadIdx.x & 63;
    if (n >= N) return;
    float adv = ad[n];
    int beg = rowstart[n], end = rowstart[n + 1];
    float acc = 0.f, ssum = 0.f;
    int j = beg;
    for (; j + 4 <= end; j += 4) {
        int s0 = csr[j + 0], s1 = csr[j + 1], s2 = csr[j + 2], s3 = csr[j + 3];
        float e0 = as[s0], e1 = as[s1], e2 = as[s2], e3 = as[s3];
        ushort v0 = h2b[(size_t)s0 * 64 + lane];
        ushort v1 = h2b[(size_t)s1 * 64 + lane];
        ushort v2 = h2b[(size_t)s2 * 64 + lane];
        ushort v3 = h2b[(size_t)s3 * 64 + lane];
        float w0 = edgew(e0 + adv), w1 = edgew(e1 + adv);
        float w2 = edgew(e2 + adv), w3 = edgew(e3 + adv);
        ssum += (w0 + w1) + (w2 + w3);
        acc += w0 * bf2f(v0) + w1 * bf2f(v1) + w2 * bf2f(v2) + w3 * bf2f(v3);
    }
    for (; j < end; j++) {
        int s0 = csr[j];
        float w0 = edgew(as[s0] + adv);
        ssum += w0;
        acc += w0 * bf2f(h2b[(size_t)s0 * 64 + lane]);
    }
    float o = acc / ssum + b2[lane];
    out2[(size_t)n * 64 + lane] = o > 0.f ? o : 0.f;
}

// ---------------------------------------------------------------- pool + final linear

__global__ __launch_bounds__(64) void k_pool(const float* __restrict__ out2,
                                             const int* __restrict__ gstart,
                                             const float* __restrict__ lin_w,
                                             const float* __restrict__ lin_b,
                                             float* __restrict__ out, int NG) {
    __shared__ float mean[64];
    int g = blockIdx.x;
    int lane = threadIdx.x;
    int beg = gstart[g], end = gstart[g + 1];
    float s = 0.f;
    for (int n = beg; n < end; n++) s += out2[(size_t)n * 64 + lane];
    float cnt = (float)(end - beg);
    mean[lane] = s / fmaxf(cnt, 1.f);
    __syncthreads();
    if (lane < NC) {
        float acc = lin_b[lane];
        #pragma unroll
        for (int c = 0; c < 64; c++) acc += mean[c] * lin_w[c * NC + lane];
        out[g * NC + lane] = acc;
    }
}

// ---------------------------------------------------------------- launch

extern "C" void kernel_launch(void* const* d_in, const int* in_sizes, int n_in,
                              void* d_out, int out_size, void* d_ws, size_t ws_size,
                              hipStream_t stream) {
    const float* x      = (const float*)d_in[0];
    const int*   ei     = (const int*)d_in[1];
    const int*   batch  = (const int*)d_in[2];
    const float* W1     = (const float*)d_in[3];
    const float* att_s1 = (const float*)d_in[4];
    const float* att_d1 = (const float*)d_in[5];
    const float* b1     = (const float*)d_in[6];
    const float* W2     = (const float*)d_in[7];
    const float* att_s2 = (const float*)d_in[8];
    const float* att_d2 = (const float*)d_in[9];
    const float* b2     = (const float*)d_in[10];
    const float* lin_w  = (const float*)d_in[11];
    const float* lin_b  = (const float*)d_in[12];
    float* out = (float*)d_out;

    const int N  = in_sizes[0] / F_IN;   // 50000
    const int E  = in_sizes[1] / 2;      // 800000
    const int NG = out_size / NC;        // 512
    const int NE = E + N;
    const int NB = (N + 1023) / 1024;    // scan blocks

    char* p = (char*)d_ws;
    auto alloc = [&](size_t bytes) { char* r = p; p += (bytes + 255) & ~(size_t)255; return r; };
    ushort* h1b     = (ushort*)alloc(sizeof(ushort) * (size_t)N * 256);
    float*  out1    = (float*)alloc(sizeof(float) * (size_t)N * 256);
    ushort* h2b     = (ushort*)alloc(sizeof(ushort) * (size_t)N * 64);
    float*  out2    = (float*)alloc(sizeof(float) * (size_t)N * 64);
    float*  as1     = (float*)alloc(sizeof(float) * (size_t)N * 4);
    float*  ad1     = (float*)alloc(sizeof(float) * (size_t)N * 4);
    float*  as2     = (float*)alloc(sizeof(float) * (size_t)N);
    float*  ad2     = (float*)alloc(sizeof(float) * (size_t)N);
    int*    rowstart= (int*)alloc(sizeof(int) * (size_t)(N + 1));
    int*    itmp    = (int*)alloc(sizeof(int) * (size_t)N);      // deg, then cursor
    int*    csr     = (int*)alloc(sizeof(int) * (size_t)NE);
    int*    counts  = (int*)alloc(sizeof(int) * (size_t)NG);
    int*    gstart  = (int*)alloc(sizeof(int) * (size_t)(NG + 1));
    int*    bsum    = (int*)alloc(sizeof(int) * 1024);
    int*    boff    = (int*)alloc(sizeof(int) * 1024);

    int bs = 256;
    // CSR build + batch counts
    k_init<<<(N + bs - 1) / bs, bs, 0, stream>>>(itmp, N, counts, NG);
    k_count<<<(E + bs - 1) / bs, bs, 0, stream>>>(ei, E, itmp);
    k_batch_count<<<(N + bs - 1) / bs, bs, 0, stream>>>(batch, N, counts);
    k_scan_part<<<NB, 1024, 0, stream>>>(itmp, rowstart, bsum, N);
    k_scan_bsum<<<1, 1024, 0, stream>>>(bsum, boff, NB, rowstart + N);
    k_scan_add_self<<<(N + 1023) / 1024, 1024, 0, stream>>>(rowstart, boff, itmp, csr, N);
    k_scan<<<1, 1024, 0, stream>>>(counts, gstart, NG);
    k_scatter<<<(E + bs - 1) / bs, bs, 0, stream>>>(ei, E, rowstart, itmp, csr);

    // layer 1 (GEMM + fused att coefs), then aggregate
    k_gemm1<<<(N + 31) / 32, 256, 0, stream>>>(x, W1, att_s1, att_d1, h1b, as1, ad1, N);
    k_agg1<<<(N + 3) / 4, 256, 0, stream>>>(h1b, as1, ad1, rowstart, csr, b1, out1, N);

    // layer 2
    k_gemm2<<<(N + 31) / 32, 256, 0, stream>>>(out1, W2, att_s2, att_d2, h2b, as2, ad2, N);
    k_agg2<<<(N + 3) / 4, 256, 0, stream>>>(h2b, as2, ad2, rowstart, csr, b2, out2, N);

    // pool + linear
    k_pool<<<NG, 64, 0, stream>>>(out2, gstart, lin_w, lin_b, out, NG);
}